// Round 3
// baseline (43.712 us; speedup 1.0000x reference)
//
#include <hip/hip_runtime.h>

// Masked MSE with ragged alignment — wave-per-row, latency-optimized.
// Phase 1: load ALL mask chunks (independent, in flight together), pack each
//          lane's 8 bools/chunk into two u32 bitmasks.
// Phase 2: 8 independent wave scans (register-only); chunk bases chain via
//          8 scalar adds instead of 8 memory-latency-separated rounds.
// Phase 3: all pred loads + rank gathers issue together.
__global__ __launch_bounds__(256, 4) void masked_mse_rows(
    const float* __restrict__ pred,
    const float* __restrict__ target,
    const int*   __restrict__ mask,
    float*       __restrict__ row_sums,
    int S, int B)
{
    const int tid  = threadIdx.x;
    const int lane = tid & 63;
    const int wid  = tid >> 6;
    const int row  = blockIdx.x * 4 + wid;
    if (row >= B) return;

    const float4* __restrict__ p4 = reinterpret_cast<const float4*>(pred + (size_t)row * S);
    const int4*   __restrict__ m4 = reinterpret_cast<const int4*>(mask + (size_t)row * S);
    const float*  __restrict__ trow = target + (size_t)row * S;

    // ---- Phase 1: mask -> per-chunk byte masks (all loads independent) ----
    unsigned bl = 0, bh = 0;   // byte c of (bl,bh) = lane's 8 mask bits for chunk c
    int cnt[8];
    #pragma unroll
    for (int c = 0; c < 8; ++c) {
        const int4 ma = m4[c * 128 + lane * 2];
        const int4 mb = m4[c * 128 + lane * 2 + 1];
        const unsigned by =
              (unsigned)(ma.x != 0)        | ((unsigned)(ma.y != 0) << 1)
            | ((unsigned)(ma.z != 0) << 2) | ((unsigned)(ma.w != 0) << 3)
            | ((unsigned)(mb.x != 0) << 4) | ((unsigned)(mb.y != 0) << 5)
            | ((unsigned)(mb.z != 0) << 6) | ((unsigned)(mb.w != 0) << 7);
        cnt[c] = __popc(by);
        if (c < 4) bl |= by << (8 * c); else bh |= by << (8 * (c - 4));
    }

    // ---- Phase 2: 8 independent wave scans, then chain chunk bases ----
    int excl[8], tot[8];
    #pragma unroll
    for (int c = 0; c < 8; ++c) {
        int s = cnt[c];
        #pragma unroll
        for (int off = 1; off < 64; off <<= 1) {
            int n = __shfl_up(s, off, 64);
            if (lane >= off) s += n;
        }
        excl[c] = s - cnt[c];
        tot[c]  = __shfl(s, 63, 64);
    }
    int base[8];
    {
        int run = 0;
        #pragma unroll
        for (int c = 0; c < 8; ++c) { base[c] = run + excl[c]; run += tot[c]; }
    }

    // ---- Phase 3: pred loads + rank gathers (ranks known, all independent) --
    float acc = 0.0f;
    #pragma unroll
    for (int c = 0; c < 8; ++c) {
        const float4 pa = p4[c * 128 + lane * 2];
        const float4 pb = p4[c * 128 + lane * 2 + 1];
        const unsigned by = ((c < 4) ? (bl >> (8 * c)) : (bh >> (8 * (c - 4)))) & 0xffu;
        int r = base[c];
        if (by & 1u)   { float d = pa.x - trow[r]; acc += d * d; ++r; }
        if (by & 2u)   { float d = pa.y - trow[r]; acc += d * d; ++r; }
        if (by & 4u)   { float d = pa.z - trow[r]; acc += d * d; ++r; }
        if (by & 8u)   { float d = pa.w - trow[r]; acc += d * d; ++r; }
        if (by & 16u)  { float d = pb.x - trow[r]; acc += d * d; ++r; }
        if (by & 32u)  { float d = pb.y - trow[r]; acc += d * d; ++r; }
        if (by & 64u)  { float d = pb.z - trow[r]; acc += d * d; ++r; }
        if (by & 128u) { float d = pb.w - trow[r]; acc += d * d; ++r; }
    }

    // wave reduction; lane 0 writes the row partial
    #pragma unroll
    for (int off = 32; off > 0; off >>= 1) acc += __shfl_down(acc, off, 64);
    if (lane == 0) row_sums[row] = acc;
}

// Deterministic final reduce of B row partials into d_out[0].
__global__ __launch_bounds__(256) void reduce_rows(
    const float* __restrict__ row_sums, float* __restrict__ out, int n)
{
    const int tid = threadIdx.x;
    float acc = 0.0f;
    for (int i = tid; i < n; i += 256) acc += row_sums[i];
    #pragma unroll
    for (int off = 32; off > 0; off >>= 1) acc += __shfl_down(acc, off, 64);
    __shared__ float facc[4];
    if ((tid & 63) == 0) facc[tid >> 6] = acc;
    __syncthreads();
    if (tid == 0) out[0] = facc[0] + facc[1] + facc[2] + facc[3];
}

extern "C" void kernel_launch(void* const* d_in, const int* in_sizes, int n_in,
                              void* d_out, int out_size, void* d_ws, size_t ws_size,
                              hipStream_t stream) {
    const float* pred   = (const float*)d_in[0];
    const float* target = (const float*)d_in[1];
    const int*   mask   = (const int*)d_in[2];
    float* out = (float*)d_out;
    float* row_sums = (float*)d_ws;

    const int S = 4096;
    const int B = in_sizes[0] / S;

    masked_mse_rows<<<(B + 3) / 4, 256, 0, stream>>>(pred, target, mask, row_sums, S, B);
    reduce_rows<<<1, 256, 0, stream>>>(row_sums, out, B);
}

// Round 4
// 35.268 us; speedup vs baseline: 1.2394x; 1.2394x over previous
//
#include <hip/hip_runtime.h>

// popcount of ballot bits strictly below this lane (wave64)
__device__ __forceinline__ int lanes_below(unsigned long long m) {
    return __builtin_amdgcn_mbcnt_hi((unsigned)(m >> 32),
           __builtin_amdgcn_mbcnt_lo((unsigned)m, 0u));
}

// Masked MSE with ragged alignment — one 512-thread block per row, single-shot.
// Row = two 2048-element chunks: chunk0 = thread's int4/float4 at [tid],
// chunk1 at [tid+512] (both fully coalesced). Rank via ballot+mbcnt (no
// dependent shuffle scan, no loop-carried chain); one LDS exchange of wave
// totals; gather target[row, rank]; accumulate.
__global__ __launch_bounds__(512, 8) void masked_mse_rows(
    const float* __restrict__ pred,
    const float* __restrict__ target,
    const int*   __restrict__ mask,
    float*       __restrict__ row_sums,
    int S)
{
    const int tid  = threadIdx.x;
    const int lane = tid & 63;
    const int wid  = tid >> 6;          // 0..7
    const int row  = blockIdx.x;

    const float4* __restrict__ p4 = reinterpret_cast<const float4*>(pred + (size_t)row * S);
    const int4*   __restrict__ m4 = reinterpret_cast<const int4*>(mask + (size_t)row * S);
    const float*  __restrict__ trow = target + (size_t)row * S;

    // all four loads independent, issued together
    const int4   ma = m4[tid];
    const int4   mb = m4[tid + 512];
    const float4 pa = p4[tid];
    const float4 pb = p4[tid + 512];

    // ballots per element slot (8 total), lane-prefix via mbcnt (pure VALU)
    const unsigned long long a0 = __ballot(ma.x != 0);
    const unsigned long long a1 = __ballot(ma.y != 0);
    const unsigned long long a2 = __ballot(ma.z != 0);
    const unsigned long long a3 = __ballot(ma.w != 0);
    const unsigned long long b0 = __ballot(mb.x != 0);
    const unsigned long long b1 = __ballot(mb.y != 0);
    const unsigned long long b2 = __ballot(mb.z != 0);
    const unsigned long long b3 = __ballot(mb.w != 0);

    const int pref_a = lanes_below(a0) + lanes_below(a1) + lanes_below(a2) + lanes_below(a3);
    const int pref_b = lanes_below(b0) + lanes_below(b1) + lanes_below(b2) + lanes_below(b3);
    const int tot_a  = __popcll(a0) + __popcll(a1) + __popcll(a2) + __popcll(a3); // wave-uniform
    const int tot_b  = __popcll(b0) + __popcll(b1) + __popcll(b2) + __popcll(b3);

    __shared__ int   ta[8], tb[8];
    __shared__ float facc[8];
    if (lane == 0) { ta[wid] = tot_a; tb[wid] = tot_b; }
    __syncthreads();

    int woff_a = 0, base_b = 0, woff_b = 0;
    #pragma unroll
    for (int w = 0; w < 8; ++w) {
        woff_a += (w < wid) ? ta[w] : 0;
        base_b += ta[w];
        woff_b += (w < wid) ? tb[w] : 0;
    }

    float acc = 0.0f;
    {
        int r = woff_a + pref_a;                       // chunk0 rank base
        if (ma.x != 0) { float d = pa.x - trow[r]; acc += d * d; ++r; }
        if (ma.y != 0) { float d = pa.y - trow[r]; acc += d * d; ++r; }
        if (ma.z != 0) { float d = pa.z - trow[r]; acc += d * d; ++r; }
        if (ma.w != 0) { float d = pa.w - trow[r]; acc += d * d; ++r; }
    }
    {
        int r = base_b + woff_b + pref_b;              // chunk1 rank base
        if (mb.x != 0) { float d = pb.x - trow[r]; acc += d * d; ++r; }
        if (mb.y != 0) { float d = pb.y - trow[r]; acc += d * d; ++r; }
        if (mb.z != 0) { float d = pb.z - trow[r]; acc += d * d; ++r; }
        if (mb.w != 0) { float d = pb.w - trow[r]; acc += d * d; ++r; }
    }

    // wave reduce, then cross-wave via LDS
    #pragma unroll
    for (int off = 32; off > 0; off >>= 1) acc += __shfl_down(acc, off, 64);
    if (lane == 0) facc[wid] = acc;
    __syncthreads();
    if (tid == 0) {
        float s = 0.0f;
        #pragma unroll
        for (int w = 0; w < 8; ++w) s += facc[w];
        row_sums[row] = s;
    }
}

// Deterministic final reduce of B row partials into d_out[0].
__global__ __launch_bounds__(1024) void reduce_rows(
    const float* __restrict__ row_sums, float* __restrict__ out, int n)
{
    const int tid = threadIdx.x;
    float acc = 0.0f;
    const int n4 = n >> 2;
    const float4* rs4 = reinterpret_cast<const float4*>(row_sums);
    for (int i = tid; i < n4; i += 1024) {
        float4 v = rs4[i];
        acc += (v.x + v.y) + (v.z + v.w);
    }
    for (int i = (n4 << 2) + tid; i < n; i += 1024) acc += row_sums[i];

    #pragma unroll
    for (int off = 32; off > 0; off >>= 1) acc += __shfl_down(acc, off, 64);
    __shared__ float facc[16];
    if ((tid & 63) == 0) facc[tid >> 6] = acc;
    __syncthreads();
    if (tid == 0) {
        float s = 0.0f;
        #pragma unroll
        for (int w = 0; w < 16; ++w) s += facc[w];
        out[0] = s;
    }
}

extern "C" void kernel_launch(void* const* d_in, const int* in_sizes, int n_in,
                              void* d_out, int out_size, void* d_ws, size_t ws_size,
                              hipStream_t stream) {
    const float* pred   = (const float*)d_in[0];
    const float* target = (const float*)d_in[1];
    const int*   mask   = (const int*)d_in[2];
    float* out = (float*)d_out;
    float* row_sums = (float*)d_ws;

    const int S = 4096;
    const int B = in_sizes[0] / S;

    masked_mse_rows<<<B, 512, 0, stream>>>(pred, target, mask, row_sums, S);
    reduce_rows<<<1, 1024, 0, stream>>>(row_sums, out, B);
}

// Round 5
// 31.196 us; speedup vs baseline: 1.4012x; 1.1305x over previous
//
#include <hip/hip_runtime.h>

// popcount of ballot bits strictly below this lane (wave64)
__device__ __forceinline__ int lanes_below(unsigned long long m) {
    return __builtin_amdgcn_mbcnt_hi((unsigned)(m >> 32),
           __builtin_amdgcn_mbcnt_lo((unsigned)m, 0u));
}

// Masked MSE with ragged alignment — one 512-thread block per row, single-shot,
// branch-free gather. Rank via ballot+mbcnt; all 8 target-gather addresses are
// computed with pure VALU before ANY gather load issues, so the 8 loads go out
// independently (one waitcnt) instead of 8 serialized exec-masked load->use
// rounds (the Round-4 critical path).
__global__ __launch_bounds__(512, 8) void masked_mse_rows(
    const float* __restrict__ pred,
    const float* __restrict__ target,
    const int*   __restrict__ mask,
    float*       __restrict__ row_sums,
    int S)
{
    const int tid  = threadIdx.x;
    const int lane = tid & 63;
    const int wid  = tid >> 6;          // 0..7
    const int row  = blockIdx.x;

    const float4* __restrict__ p4 = reinterpret_cast<const float4*>(pred + (size_t)row * S);
    const int4*   __restrict__ m4 = reinterpret_cast<const int4*>(mask + (size_t)row * S);
    const float*  __restrict__ trow = target + (size_t)row * S;

    // all four big loads independent, issued together
    const int4   ma = m4[tid];
    const int4   mb = m4[tid + 512];
    const float4 pa = p4[tid];
    const float4 pb = p4[tid + 512];

    const int c0 = (ma.x != 0), c1 = (ma.y != 0), c2 = (ma.z != 0), c3 = (ma.w != 0);
    const int c4 = (mb.x != 0), c5 = (mb.y != 0), c6 = (mb.z != 0), c7 = (mb.w != 0);

    // ballots per element slot, lane-prefix via mbcnt (pure VALU, no scan chain)
    const unsigned long long a0 = __ballot(c0);
    const unsigned long long a1 = __ballot(c1);
    const unsigned long long a2 = __ballot(c2);
    const unsigned long long a3 = __ballot(c3);
    const unsigned long long b0 = __ballot(c4);
    const unsigned long long b1 = __ballot(c5);
    const unsigned long long b2 = __ballot(c6);
    const unsigned long long b3 = __ballot(c7);

    const int pref_a = lanes_below(a0) + lanes_below(a1) + lanes_below(a2) + lanes_below(a3);
    const int pref_b = lanes_below(b0) + lanes_below(b1) + lanes_below(b2) + lanes_below(b3);
    const int tot_a  = __popcll(a0) + __popcll(a1) + __popcll(a2) + __popcll(a3); // wave-uniform
    const int tot_b  = __popcll(b0) + __popcll(b1) + __popcll(b2) + __popcll(b3);

    __shared__ int   ta[8], tb[8];
    __shared__ float facc[8];
    if (lane == 0) { ta[wid] = tot_a; tb[wid] = tot_b; }
    __syncthreads();

    int woff_a = 0, base_b = 0, woff_b = 0;
    #pragma unroll
    for (int w = 0; w < 8; ++w) {
        woff_a += (w < wid) ? ta[w] : 0;
        base_b += ta[w];
        woff_b += (w < wid) ? tb[w] : 0;
    }

    // ---- branch-free: all 8 gather addresses first (pure VALU chain) ----
    int idx[8];
    {
        int r = woff_a + pref_a;
        idx[0] = r; r += c0;
        idx[1] = r; r += c1;
        idx[2] = r; r += c2;
        idx[3] = r; r += c3;
    }
    {
        int r = base_b + woff_b + pref_b;
        idx[4] = r; r += c4;
        idx[5] = r; r += c5;
        idx[6] = r; r += c6;
        idx[7] = r; r += c7;
    }
    // addresses are provably <= S-1 (count of masked positions strictly before
    // a slot; == S only if all S masked, in which case every slot is masked
    // with rank <= S-1), so unconditional loads are in-bounds.
    float tv[8];
    #pragma unroll
    for (int j = 0; j < 8; ++j) tv[j] = trow[idx[j]];   // 8 independent loads

    const float pv[8] = {pa.x, pa.y, pa.z, pa.w, pb.x, pb.y, pb.z, pb.w};
    const int   cs[8] = {c0, c1, c2, c3, c4, c5, c6, c7};
    float acc = 0.0f;
    #pragma unroll
    for (int j = 0; j < 8; ++j) {
        const float d = pv[j] - tv[j];
        acc += cs[j] ? d * d : 0.0f;
    }

    // wave reduce, then cross-wave via LDS
    #pragma unroll
    for (int off = 32; off > 0; off >>= 1) acc += __shfl_down(acc, off, 64);
    if (lane == 0) facc[wid] = acc;
    __syncthreads();
    if (tid == 0) {
        float s = 0.0f;
        #pragma unroll
        for (int w = 0; w < 8; ++w) s += facc[w];
        row_sums[row] = s;
    }
}

// Deterministic final reduce of B row partials into d_out[0].
__global__ __launch_bounds__(1024) void reduce_rows(
    const float* __restrict__ row_sums, float* __restrict__ out, int n)
{
    const int tid = threadIdx.x;
    float acc = 0.0f;
    const int n4 = n >> 2;
    const float4* rs4 = reinterpret_cast<const float4*>(row_sums);
    for (int i = tid; i < n4; i += 1024) {
        float4 v = rs4[i];
        acc += (v.x + v.y) + (v.z + v.w);
    }
    for (int i = (n4 << 2) + tid; i < n; i += 1024) acc += row_sums[i];

    #pragma unroll
    for (int off = 32; off > 0; off >>= 1) acc += __shfl_down(acc, off, 64);
    __shared__ float facc[16];
    if ((tid & 63) == 0) facc[tid >> 6] = acc;
    __syncthreads();
    if (tid == 0) {
        float s = 0.0f;
        #pragma unroll
        for (int w = 0; w < 16; ++w) s += facc[w];
        out[0] = s;
    }
}

extern "C" void kernel_launch(void* const* d_in, const int* in_sizes, int n_in,
                              void* d_out, int out_size, void* d_ws, size_t ws_size,
                              hipStream_t stream) {
    const float* pred   = (const float*)d_in[0];
    const float* target = (const float*)d_in[1];
    const int*   mask   = (const int*)d_in[2];
    float* out = (float*)d_out;
    float* row_sums = (float*)d_ws;

    const int S = 4096;
    const int B = in_sizes[0] / S;

    masked_mse_rows<<<B, 512, 0, stream>>>(pred, target, mask, row_sums, S);
    reduce_rows<<<1, 1024, 0, stream>>>(row_sums, out, B);
}